// Round 11
// baseline (717.510 us; speedup 1.0000x reference)
//
#include <hip/hip_runtime.h>
#include <hip/hip_bf16.h>

typedef __bf16 bf16x8 __attribute__((ext_vector_type(8)));
typedef float f32x4 __attribute__((ext_vector_type(4)));
typedef _Float16 h8 __attribute__((ext_vector_type(8)));
typedef unsigned short u16x8 __attribute__((ext_vector_type(8)));

__device__ inline unsigned short f2b(float x) {
    __hip_bfloat16 h = __float2bfloat16(x);
    return __builtin_bit_cast(unsigned short, h);
}

__device__ inline void gload16(const void* g, void* l) {
    __builtin_amdgcn_global_load_lds(
        (const __attribute__((address_space(1))) unsigned int*)g,
        (__attribute__((address_space(3))) unsigned int*)l, 16, 0, 0);
}

#define BAR  asm volatile("s_barrier" ::: "memory")
#define VMC(N) asm volatile("s_waitcnt vmcnt(" #N ")" ::: "memory")

// ===========================================================================
// 512-thread / 8-wave GEMM (r6-exact, verified best for QKV / out)
// ===========================================================================

#define RD_A(BASE, MO)                                                \
    af[0][0] = *(const bf16x8*)((BASE) + (MO) * 1024 + aoff0);        \
    af[0][1] = *(const bf16x8*)((BASE) + (MO) * 1024 + aoff1);        \
    af[1][0] = *(const bf16x8*)((BASE) + ((MO) + 1) * 1024 + aoff0);  \
    af[1][1] = *(const bf16x8*)((BASE) + ((MO) + 1) * 1024 + aoff1);

#define RD_B(BASE)                                                    \
    _Pragma("unroll")                                                 \
    for (int n_ = 0; n_ < 4; ++n_) {                                  \
        bfr[n_][0] = *(const bf16x8*)((BASE) + n_ * 1024 + aoff0);    \
        bfr[n_][1] = *(const bf16x8*)((BASE) + n_ * 1024 + aoff1);    \
    }

#define MFMA_Q(MO)                                                    \
    __builtin_amdgcn_s_setprio(1);                                    \
    _Pragma("unroll")                                                 \
    for (int kk_ = 0; kk_ < 2; ++kk_)                                 \
        _Pragma("unroll")                                             \
        for (int mi_ = 0; mi_ < 2; ++mi_)                             \
            _Pragma("unroll")                                         \
            for (int n_ = 0; n_ < 4; ++n_)                            \
                acc[(MO) + mi_][n_] =                                 \
                    __builtin_amdgcn_mfma_f32_16x16x32_bf16(          \
                        af[mi_][kk_], bfr[n_][kk_],                   \
                        acc[(MO) + mi_][n_], 0, 0, 0);                \
    __builtin_amdgcn_s_setprio(0);

// EPI: 0 = QKV router (bias, q/k normal, v transposed), 3 = f32+bias
template<int EPI, int SWZ>
__global__ __launch_bounds__(512, 2) void gemm_nt(
    const unsigned short* __restrict__ A, const unsigned short* __restrict__ B,
    long aZ, long bZ, int lda, int ldb, int K,
    const float* __restrict__ bias,
    void* __restrict__ C0, void* __restrict__ C1, void* __restrict__ C2,
    long cZ, int ldc, float scale, int gx, int gy)
{
    __shared__ __attribute__((aligned(16))) unsigned short lds[2][4][8192];

    int wgid;
    if (SWZ) {
        const int nwg = (int)gridDim.x;
        const int bid = (int)blockIdx.x;
        const int qch = nwg >> 3, rch = nwg & 7;
        const int xcd = bid & 7, idx = bid >> 3;
        wgid = (xcd < rch ? xcd * (qch + 1)
                          : rch * (qch + 1) + (xcd - rch) * qch) + idx;
    } else {
        wgid = (int)blockIdx.x;
    }
    const int bx = wgid % gx;
    const int rem = wgid / gx;
    const int by = rem % gy;
    const int z = rem / gy;

    const int t = threadIdx.x;
    const int lane = t & 63, wid = t >> 6;
    const int wr = wid >> 2, wc = wid & 3;           // 2 x 4 wave grid
    const int tileM = by * 256, tileN = bx * 256;
    A += (size_t)z * aZ;
    B += (size_t)z * bZ;

    f32x4 acc[8][4] = {};

    const int l4 = lane & 15, qw = lane >> 4, sw = lane & 7;
    const int aoff0 = l4 * 64 + ((qw ^ sw) << 3);
    const int aoff1 = l4 * 64 + (((4 | qw) ^ sw) << 3);

    const unsigned short* aB0 = &lds[0][wr][0];
    const unsigned short* aB1 = &lds[1][wr][0];
    const unsigned short* bB0 = &lds[0][2 + (wc >> 1)][0] + (wc & 1) * 4096;
    const unsigned short* bB1 = &lds[1][2 + (wc >> 1)][0] + (wc & 1) * 4096;

    char* const ldsA[2] = {(char*)&lds[0][0][0], (char*)&lds[1][0][0]};
    char* const ldsB[2] = {(char*)&lds[0][2][0], (char*)&lds[1][2][0]};

    const int srow = t >> 3;
    const int sg = ((t ^ (t >> 3)) & 7) << 3;
    const unsigned short* Asrc0 = A + (size_t)(tileM + srow) * lda + sg;
    const unsigned short* Asrc1 = Asrc0 + (size_t)128 * lda;
    const unsigned short* Bsrc0 = B + (size_t)(tileN + srow) * ldb + sg;
    const unsigned short* Bsrc1 = Bsrc0 + (size_t)128 * ldb;

    auto stageA = [&](char* Lb, int koff, int h) {
        char* dst = Lb + h * 16384 + wid * 1024;
        const unsigned short* s = (h ? Asrc1 : Asrc0) + koff;
        gload16(s, dst);
        gload16(s + (size_t)64 * lda, dst + 8192);
    };
    auto stageB = [&](char* Lb, int koff, int h) {
        char* dst = Lb + h * 16384 + wid * 1024;
        const unsigned short* s = (h ? Bsrc1 : Bsrc0) + koff;
        gload16(s, dst);
        gload16(s + (size_t)64 * ldb, dst + 8192);
    };

    const int NT = K >> 6;
    const int NI = NT >> 1;

    stageA(ldsA[0], 0, 0); stageA(ldsA[0], 0, 1);
    stageB(ldsB[0], 0, 0); stageB(ldsB[0], 0, 1);
    stageB(ldsB[1], 64, 0); stageB(ldsB[1], 64, 1);
    VMC(4);
    BAR;

    bf16x8 af[2][2], bfr[4][2];

#pragma unroll 1
    for (int i = 0; i < NI - 1; ++i) {
        const int kb = i * 128;
        const int ko = kb + 64, ke2 = kb + 128, ko2 = kb + 192;

        RD_B(bB0); RD_A(aB0, 0);
        BAR; stageA(ldsA[1], ko, 0);
        MFMA_Q(0)
        RD_A(aB0, 2);
        BAR; stageA(ldsA[1], ko, 1);
        MFMA_Q(2)
        RD_A(aB0, 4);
        BAR; stageB(ldsB[0], ke2, 0);
        MFMA_Q(4)
        RD_A(aB0, 6);
        VMC(2);
        BAR; stageB(ldsB[0], ke2, 1);
        MFMA_Q(6)
        RD_B(bB1); RD_A(aB1, 0);
        BAR; stageA(ldsA[0], ke2, 0);
        MFMA_Q(0)
        RD_A(aB1, 2);
        BAR; stageA(ldsA[0], ke2, 1);
        MFMA_Q(2)
        RD_A(aB1, 4);
        BAR; stageB(ldsB[1], ko2, 0);
        MFMA_Q(4)
        RD_A(aB1, 6);
        VMC(2);
        BAR; stageB(ldsB[1], ko2, 1);
        MFMA_Q(6)
    }

    {
        const int ko = (NI - 1) * 128 + 64;
        RD_B(bB0); RD_A(aB0, 0);
        BAR; stageA(ldsA[1], ko, 0);
        MFMA_Q(0)
        RD_A(aB0, 2);
        BAR; stageA(ldsA[1], ko, 1);
        MFMA_Q(2)
        RD_A(aB0, 4);
        BAR;
        MFMA_Q(4)
        RD_A(aB0, 6);
        VMC(0);
        BAR;
        MFMA_Q(6)
        RD_B(bB1); RD_A(aB1, 0);
        BAR;
        MFMA_Q(0)
        RD_A(aB1, 2);
        BAR;
        MFMA_Q(2)
        RD_A(aB1, 4);
        BAR;
        MFMA_Q(4)
        RD_A(aB1, 6);
        BAR;
        MFMA_Q(6)
    }

    const int lr = lane >> 4, lc = lane & 15;
#pragma unroll
    for (int m = 0; m < 8; ++m) {
#pragma unroll
        for (int n = 0; n < 4; ++n) {
            f32x4 v = acc[m][n];
            const int col = tileN + wc * 64 + n * 16 + lc;
            const int row0 = tileM + wr * 128 + m * 16 + lr * 4;
            if (EPI == 0) {
                const float bv = bias[col];
                if (col < 2048) {
                    unsigned short* dst = (col < 1024) ? (unsigned short*)C0
                                                       : (unsigned short*)C1;
                    const int cc = col & 1023;
#pragma unroll
                    for (int j = 0; j < 4; ++j)
                        dst[(size_t)(row0 + j) * 1024 + cc] = f2b(v[j] + bv);
                } else {
                    const int b = row0 >> 12, s = row0 & 4095;
                    ushort4 h4;
                    h4.x = f2b(v[0] + bv); h4.y = f2b(v[1] + bv);
                    h4.z = f2b(v[2] + bv); h4.w = f2b(v[3] + bv);
                    *(ushort4*)((unsigned short*)C2 +
                                ((size_t)b * 1024 + (col - 2048)) * 4096 + s) = h4;
                }
            } else {
#pragma unroll
                for (int j = 0; j < 4; ++j)
                    ((float*)C0)[(size_t)(row0 + j) * ldc + col] = v[j] + bias[col];
            }
        }
    }
}

// ===========================================================================
// 1024-thread / 16-wave GEMM (scores / PV): same 256x256 tile, BK=64, same
// LDS layout/swizzle/phase skeleton as r6, but 4Mx4N wave grid (wave tile
// 64x64, acc=64 regs) -> <=128 unified regs/wave -> 4 waves/SIMD (2x TLP).
// Stage call = 1 gload16/thread (1024x16B = one 128x64 half-tile).
// Seals at 1-load granularity: VMC(1) (leave newest stage call flying) ==
// r6's VMC(2) at 2-load granularity; prologue VMC(2) (B(1) flies), tail 0.
// EPI: 1 = f16*scale (scores), 2 = bf16 (PV->ao)
// ===========================================================================

#define RD_A16(BASE, MF)                                              \
    afc[0] = *(const bf16x8*)((BASE) + (MF) * 1024 + aoff0);          \
    afc[1] = *(const bf16x8*)((BASE) + (MF) * 1024 + aoff1);

#define MFMA_W(MF)                                                    \
    __builtin_amdgcn_s_setprio(1);                                    \
    _Pragma("unroll")                                                 \
    for (int n_ = 0; n_ < 4; ++n_) {                                  \
        acc[MF][n_] = __builtin_amdgcn_mfma_f32_16x16x32_bf16(        \
            afc[0], bfr[n_][0], acc[MF][n_], 0, 0, 0);                \
        acc[MF][n_] = __builtin_amdgcn_mfma_f32_16x16x32_bf16(        \
            afc[1], bfr[n_][1], acc[MF][n_], 0, 0, 0);                \
    }                                                                 \
    __builtin_amdgcn_s_setprio(0);

template<int EPI, int SWZ>
__global__ __launch_bounds__(1024, 4) void gemm_nt16(
    const unsigned short* __restrict__ A, const unsigned short* __restrict__ B,
    long aZ, long bZ, int lda, int ldb, int K,
    void* __restrict__ C0, long cZ, int ldc, float scale, int gx, int gy)
{
    __shared__ __attribute__((aligned(16))) unsigned short lds[2][4][8192];

    int wgid;
    if (SWZ) {
        const int nwg = (int)gridDim.x;
        const int bid = (int)blockIdx.x;
        const int qch = nwg >> 3, rch = nwg & 7;
        const int xcd = bid & 7, idx = bid >> 3;
        wgid = (xcd < rch ? xcd * (qch + 1)
                          : rch * (qch + 1) + (xcd - rch) * qch) + idx;
    } else {
        wgid = (int)blockIdx.x;
    }
    const int bx = wgid % gx;
    const int rem = wgid / gx;
    const int by = rem % gy;
    const int z = rem / gy;

    const int t = threadIdx.x;
    const int lane = t & 63, wid = t >> 6;
    const int wr = wid >> 2, wc = wid & 3;           // 4 x 4 wave grid
    const int tileM = by * 256, tileN = bx * 256;
    A += (size_t)z * aZ;
    B += (size_t)z * bZ;

    f32x4 acc[4][4] = {};                            // wave tile 64x64

    const int l4 = lane & 15, qw = lane >> 4, sw = lane & 7;
    const int aoff0 = l4 * 64 + ((qw ^ sw) << 3);
    const int aoff1 = l4 * 64 + (((4 | qw) ^ sw) << 3);

    // A read base: wave wr owns rows wr*64.. -> half (wr>>1), slice (wr&1)*64
    const unsigned short* aB0 = &lds[0][wr >> 1][0] + (wr & 1) * 4096;
    const unsigned short* aB1 = &lds[1][wr >> 1][0] + (wr & 1) * 4096;
    const unsigned short* bB0 = &lds[0][2 + (wc >> 1)][0] + (wc & 1) * 4096;
    const unsigned short* bB1 = &lds[1][2 + (wc >> 1)][0] + (wc & 1) * 4096;

    char* const ldsA[2] = {(char*)&lds[0][0][0], (char*)&lds[1][0][0]};
    char* const ldsB[2] = {(char*)&lds[0][2][0], (char*)&lds[1][2][0]};

    // staging: 1024 threads, 1 chunk each per half-tile (row t>>3, gran t&7)
    const int srow = t >> 3;
    const int sg = ((t ^ (t >> 3)) & 7) << 3;
    const unsigned short* Asrc0 = A + (size_t)(tileM + srow) * lda + sg;
    const unsigned short* Asrc1 = Asrc0 + (size_t)128 * lda;
    const unsigned short* Bsrc0 = B + (size_t)(tileN + srow) * ldb + sg;
    const unsigned short* Bsrc1 = Bsrc0 + (size_t)128 * ldb;

    auto stageA = [&](char* Lb, int koff, int h) {
        gload16((h ? Asrc1 : Asrc0) + koff, Lb + h * 16384 + t * 16);
    };
    auto stageB = [&](char* Lb, int koff, int h) {
        gload16((h ? Bsrc1 : Bsrc0) + koff, Lb + h * 16384 + t * 16);
    };

    const int NT = K >> 6;
    const int NI = NT >> 1;

    stageA(ldsA[0], 0, 0); stageA(ldsA[0], 0, 1);
    stageB(ldsB[0], 0, 0); stageB(ldsB[0], 0, 1);
    stageB(ldsB[1], 64, 0); stageB(ldsB[1], 64, 1);
    VMC(2);                                          // tile0 landed, B(1) fly
    BAR;

    bf16x8 afc[2], bfr[4][2];

#pragma unroll 1
    for (int i = 0; i < NI - 1; ++i) {
        const int kb = i * 128;
        const int ko = kb + 64, ke2 = kb + 128, ko2 = kb + 192;

        RD_B(bB0); RD_A16(aB0, 0);
        BAR; stageA(ldsA[1], ko, 0);
        MFMA_W(0)
        RD_A16(aB0, 1);
        BAR; stageA(ldsA[1], ko, 1);
        MFMA_W(1)
        RD_A16(aB0, 2);
        BAR; stageB(ldsB[0], ke2, 0);
        MFMA_W(2)
        RD_A16(aB0, 3);
        VMC(1);                                      // tile o landed
        BAR; stageB(ldsB[0], ke2, 1);
        MFMA_W(3)
        RD_B(bB1); RD_A16(aB1, 0);
        BAR; stageA(ldsA[0], ke2, 0);
        MFMA_W(0)
        RD_A16(aB1, 1);
        BAR; stageA(ldsA[0], ke2, 1);
        MFMA_W(1)
        RD_A16(aB1, 2);
        BAR; stageB(ldsB[1], ko2, 0);
        MFMA_W(2)
        RD_A16(aB1, 3);
        VMC(1);                                      // tile e+2 landed
        BAR; stageB(ldsB[1], ko2, 1);
        MFMA_W(3)
    }

    {   // peeled final iteration
        const int ko = (NI - 1) * 128 + 64;
        RD_B(bB0); RD_A16(aB0, 0);
        BAR; stageA(ldsA[1], ko, 0);
        MFMA_W(0)
        RD_A16(aB0, 1);
        BAR; stageA(ldsA[1], ko, 1);
        MFMA_W(1)
        RD_A16(aB0, 2);
        BAR;
        MFMA_W(2)
        RD_A16(aB0, 3);
        VMC(0);
        BAR;
        MFMA_W(3)
        RD_B(bB1); RD_A16(aB1, 0);
        BAR;
        MFMA_W(0)
        RD_A16(aB1, 1);
        BAR;
        MFMA_W(1)
        RD_A16(aB1, 2);
        BAR;
        MFMA_W(2)
        RD_A16(aB1, 3);
        BAR;
        MFMA_W(3)
    }

    // epilogue: col = lane&15, row = (lane>>4)*4 + j  [m89-verified]
    const int lr = lane >> 4, lc = lane & 15;
#pragma unroll
    for (int m = 0; m < 4; ++m) {
#pragma unroll
        for (int n = 0; n < 4; ++n) {
            f32x4 v = acc[m][n];
            const int col = tileN + wc * 64 + n * 16 + lc;
            const int row0 = tileM + wr * 64 + m * 16 + lr * 4;
            if (EPI == 1) {
#pragma unroll
                for (int j = 0; j < 4; ++j)
                    ((_Float16*)C0)[(size_t)z * cZ + (size_t)(row0 + j) * ldc + col] =
                        (_Float16)(v[j] * scale);
            } else {
#pragma unroll
                for (int j = 0; j < 4; ++j)
                    ((unsigned short*)C0)[(size_t)z * cZ + (size_t)(row0 + j) * ldc + col] =
                        f2b(v[j]);
            }
        }
    }
}

// ---------------------------------------------------------------------------
// Row softmax in-place: reads 4096 f16, writes 4096 bf16 over the same bytes.
// ---------------------------------------------------------------------------
__global__ __launch_bounds__(256) void softmax_rows(unsigned short* __restrict__ sc)
{
    const size_t rowoff = (size_t)blockIdx.x * 4096;
    const int t = threadIdx.x;

    h8 a = *(const h8*)(sc + rowoff + t * 8);
    h8 b = *(const h8*)(sc + rowoff + 2048 + t * 8);
    float v[16];
#pragma unroll
    for (int i = 0; i < 8; ++i) { v[i] = (float)a[i]; v[8 + i] = (float)b[i]; }

    float mx = -1e30f;
#pragma unroll
    for (int i = 0; i < 16; ++i) mx = fmaxf(mx, v[i]);
#pragma unroll
    for (int o = 32; o > 0; o >>= 1) mx = fmaxf(mx, __shfl_xor(mx, o));
    __shared__ float redm[4];
    if ((t & 63) == 0) redm[t >> 6] = mx;
    __syncthreads();
    mx = fmaxf(fmaxf(redm[0], redm[1]), fmaxf(redm[2], redm[3]));

    float sum = 0.f;
#pragma unroll
    for (int i = 0; i < 16; ++i) { v[i] = __expf(v[i] - mx); sum += v[i]; }
#pragma unroll
    for (int o = 32; o > 0; o >>= 1) sum += __shfl_xor(sum, o);
    __shared__ float reds[4];
    if ((t & 63) == 0) reds[t >> 6] = sum;
    __syncthreads();
    sum = reds[0] + reds[1] + reds[2] + reds[3];
    const float rs = 1.f / sum;

    u16x8 w0, w1;
#pragma unroll
    for (int i = 0; i < 8; ++i) {
        w0[i] = f2b(v[i] * rs);
        w1[i] = f2b(v[8 + i] * rs);
    }
    *(u16x8*)(sc + rowoff + t * 8) = w0;
    *(u16x8*)(sc + rowoff + 2048 + t * 8) = w1;
}

__global__ __launch_bounds__(256) void cast_bf16(
    const float* __restrict__ in, unsigned short* __restrict__ out, int n4)
{
    const int i = blockIdx.x * 256 + threadIdx.x;
    if (i < n4) {
        float4 f = ((const float4*)in)[i];
        ushort4 o;
        o.x = f2b(f.x); o.y = f2b(f.y); o.z = f2b(f.z); o.w = f2b(f.w);
        ((ushort4*)out)[i] = o;
    }
}

// ---------------------------------------------------------------------------
extern "C" void kernel_launch(void* const* d_in, const int* in_sizes, int n_in,
                              void* d_out, int out_size, void* d_ws, size_t ws_size,
                              hipStream_t stream)
{
    const float* x      = (const float*)d_in[0];   // [4,4096,1024]
    const float* qkv_w  = (const float*)d_in[1];   // [3072,1024]
    const float* qkv_b  = (const float*)d_in[2];   // [3072]
    const float* out_w  = (const float*)d_in[3];   // [1024,1024]
    const float* out_b  = (const float*)d_in[4];   // [1024]
    float* out = (float*)d_out;                    // [4,4096,1024] fp32

    unsigned short* W = (unsigned short*)d_ws;
    const size_t M16 = 16777216;   // one [4,4096,1024] bf16 tensor (ushorts)

    if (ws_size >= 236978176ull) {
        // ---- big mode: 226 MiB peak ----
        unsigned short* sc   = W;
        unsigned short* q    = sc + 67108864;
        unsigned short* kk   = q + M16;
        unsigned short* vT   = kk + M16;
        unsigned short* wo   = vT + M16;
        unsigned short* xb   = sc;            // transient, dead before sc write
        unsigned short* wqkv = sc + M16;      // transient
        unsigned short* ao   = q;             // q dead after scores GEMM

        cast_bf16<<<16384, 256, 0, stream>>>(x, xb, 4194304);
        cast_bf16<<<3072, 256, 0, stream>>>(qkv_w, wqkv, 786432);
        cast_bf16<<<1024, 256, 0, stream>>>(out_w, wo, 262144);

        gemm_nt<0, 0><<<12 * 64, 512, 0, stream>>>(
            xb, wqkv, 0, 0, 1024, 1024, 1024, qkv_b, q, kk, vT, 0, 0, 0.f, 12, 64);

        gemm_nt16<1, 0><<<16 * 16 * 4, 1024, 0, stream>>>(
            q, kk, 4194304, 4194304, 1024, 1024, 1024,
            sc, 16777216, 4096, 0.03125f, 16, 16);

        softmax_rows<<<16384, 256, 0, stream>>>(sc);

        gemm_nt16<2, 1><<<4 * 16 * 4, 1024, 0, stream>>>(
            sc, vT, 16777216, 4194304, 4096, 4096, 4096,
            ao, 4194304, 1024, 0.f, 4, 16);

        gemm_nt<3, 0><<<4 * 64, 512, 0, stream>>>(
            ao, wo, 0, 0, 1024, 1024, 1024, out_b,
            out, nullptr, nullptr, 0, 1024, 0.f, 4, 64);
    } else {
        // ---- small mode: 168 MiB peak, per-batch scores buffer ----
        unsigned short* sc   = W;
        unsigned short* q    = sc + M16;
        unsigned short* kk   = q + M16;
        unsigned short* vT   = kk + M16;
        unsigned short* ao   = vT + M16;
        unsigned short* wo   = ao + M16;
        unsigned short* wqkv = wo + 1048576;
        unsigned short* xb   = sc;

        cast_bf16<<<16384, 256, 0, stream>>>(x, xb, 4194304);
        cast_bf16<<<3072, 256, 0, stream>>>(qkv_w, wqkv, 786432);
        cast_bf16<<<1024, 256, 0, stream>>>(out_w, wo, 262144);

        gemm_nt<0, 0><<<12 * 64, 512, 0, stream>>>(
            xb, wqkv, 0, 0, 1024, 1024, 1024, qkv_b, q, kk, vT, 0, 0, 0.f, 12, 64);

        for (int z = 0; z < 4; ++z) {
            const size_t zo = (size_t)z * 4194304;
            gemm_nt16<1, 0><<<16 * 16, 1024, 0, stream>>>(
                q + zo, kk + zo, 0, 0, 1024, 1024, 1024,
                sc, 0, 4096, 0.03125f, 16, 16);
            softmax_rows<<<4096, 256, 0, stream>>>(sc);
            gemm_nt16<2, 1><<<4 * 16, 1024, 0, stream>>>(
                sc, vT + zo, 0, 0, 4096, 4096, 4096,
                ao + zo, 0, 1024, 0.f, 4, 16);
        }

        gemm_nt<3, 0><<<4 * 64, 512, 0, stream>>>(
            ao, wo, 0, 0, 1024, 1024, 1024, out_b,
            out, nullptr, nullptr, 0, 1024, 0.f, 4, 64);
    }
}

// Round 12
// 442.790 us; speedup vs baseline: 1.6204x; 1.6204x over previous
//
#include <hip/hip_runtime.h>
#include <hip/hip_bf16.h>

typedef __bf16 bf16x8 __attribute__((ext_vector_type(8)));
typedef float f32x4 __attribute__((ext_vector_type(4)));
typedef _Float16 h8 __attribute__((ext_vector_type(8)));
typedef unsigned short u16x8 __attribute__((ext_vector_type(8)));

__device__ inline unsigned short f2b(float x) {
    __hip_bfloat16 h = __float2bfloat16(x);
    return __builtin_bit_cast(unsigned short, h);
}

__device__ inline void gload16(const void* g, void* l) {
    __builtin_amdgcn_global_load_lds(
        (const __attribute__((address_space(1))) unsigned int*)g,
        (__attribute__((address_space(3))) unsigned int*)l, 16, 0, 0);
}

#define BAR  asm volatile("s_barrier" ::: "memory")
#define VMC(N) asm volatile("s_waitcnt vmcnt(" #N ")" ::: "memory")

// reads for one quadrant's A operands (m rows MO, MO+1; both k-halves)
#define RD_A(BASE, MO)                                                \
    af[0][0] = *(const bf16x8*)((BASE) + (MO) * 1024 + aoff0);        \
    af[0][1] = *(const bf16x8*)((BASE) + (MO) * 1024 + aoff1);        \
    af[1][0] = *(const bf16x8*)((BASE) + ((MO) + 1) * 1024 + aoff0);  \
    af[1][1] = *(const bf16x8*)((BASE) + ((MO) + 1) * 1024 + aoff1);

#define RD_B(BASE)                                                    \
    _Pragma("unroll")                                                 \
    for (int n_ = 0; n_ < 4; ++n_) {                                  \
        bfr[n_][0] = *(const bf16x8*)((BASE) + n_ * 1024 + aoff0);    \
        bfr[n_][1] = *(const bf16x8*)((BASE) + n_ * 1024 + aoff1);    \
    }

// 16 MFMA: quadrant m in {MO, MO+1} x 4 n x 2 kk, static acc indices.
// Compiler inserts the lgkm waits before first af/bfr use (rule-#18-safe).
#define MFMA_Q(MO)                                                    \
    __builtin_amdgcn_s_setprio(1);                                    \
    _Pragma("unroll")                                                 \
    for (int kk_ = 0; kk_ < 2; ++kk_)                                 \
        _Pragma("unroll")                                             \
        for (int mi_ = 0; mi_ < 2; ++mi_)                             \
            _Pragma("unroll")                                         \
            for (int n_ = 0; n_ < 4; ++n_)                            \
                acc[(MO) + mi_][n_] =                                 \
                    __builtin_amdgcn_mfma_f32_16x16x32_bf16(          \
                        af[mi_][kk_], bfr[n_][kk_],                   \
                        acc[(MO) + mi_][n_], 0, 0, 0);                \
    __builtin_amdgcn_s_setprio(0);

// ---------------------------------------------------------------------------
// NT GEMM: C[M,N] = A[M,K] * B[N,K]^T (+bias), A/B bf16 K-contiguous.
// Session-best configuration (r6, 441.9us total; GEMM 132.5us, MfmaUtil 46%,
// 0 bank conflicts, 0 spill): 8-phase / 2-K-tile schedule, ONE barrier per
// phase, stage issued in the MFMA shadow. 256x256 tile, BK=64, 512 thr =
// 8 waves (2Mx4N), wave tile 128x64, mfma 16x16x32.
// LDS = 2 bufs x [A0|A1|B0|B1] x 16KiB = 128 KiB.
// Phase p: { 4 (or 12) ds_read; [seal vmcnt before BAR at p3/p7]; s_barrier;
//            stage 1 half-tile (2 gload_lds, post-barrier -> overlaps MFMA);
//            setprio(1); 16 MFMA; setprio(0) }
// Safety: a wave arrives at BAR(p+1) only after MFMA(p) issued, which is
// after its phase-p reads drained (compiler lgkm wait) -> all waves past a
// barrier implies all previous-phase reads drained; every LDS overwrite has
// >=1 phase separation from its region's last read. Stages: p0/p1: A(o);
// p2/p3: B(e+2); p4/p5: A(e+2); p6/p7: B(o+2). Seals: VMC(2) before BAR3
// (tile o landed; newest half B0(e+2) flies) and before BAR7 (tile e+2
// landed; B0(o+2) flies) — never 0 mid-loop (T4). Tail iter peeled
// (branch-free steady loop), seals VMC(0) at its p3.
// Swizzle (0-conflict): 16B granule g' = g ^ (row&7); source pre-swizzled
// within the row's 128B line, gload_lds dest linear, ds_read applies the
// same involution (both-sides rule #21).
// Falsified perturbations (counters on file): cross-phase reg pre-read
// (r3/r7: lgkm re-serialization / spill), 32x32 MFMA + fewer barriers (r4:
// neutral), fp32-A cast fusion (r8: L3 footprint doubling), ring-3 A (r9:
// overhead > seal savings), XCD swizzle + __expf (r10: null), 16-wave TLP
// (r11: forced spill at 128-reg cap). r6 sits at the 256-unified-reg/wave
// boundary with LDS-read ~= MFMA content — the constrained optimum of this
// decomposition.
// EPI: 0 = QKV router (bias, q/k normal, v transposed), 1 = f16*scale (scores),
//      2 = bf16 (PV->ao), 3 = f32+bias (final out)
// ---------------------------------------------------------------------------
template<int EPI, int SWZ>
__global__ __launch_bounds__(512, 2) void gemm_nt(
    const unsigned short* __restrict__ A, const unsigned short* __restrict__ B,
    long aZ, long bZ, int lda, int ldb, int K,
    const float* __restrict__ bias,
    void* __restrict__ C0, void* __restrict__ C1, void* __restrict__ C2,
    long cZ, int ldc, float scale, int gx, int gy)
{
    __shared__ __attribute__((aligned(16))) unsigned short lds[2][4][8192];

    int wgid;
    if (SWZ) {
        const int nwg = (int)gridDim.x;
        const int bid = (int)blockIdx.x;
        const int qch = nwg >> 3, rch = nwg & 7;
        const int xcd = bid & 7, idx = bid >> 3;
        wgid = (xcd < rch ? xcd * (qch + 1)
                          : rch * (qch + 1) + (xcd - rch) * qch) + idx;
    } else {
        wgid = (int)blockIdx.x;
    }
    const int bx = wgid % gx;
    const int rem = wgid / gx;
    const int by = rem % gy;
    const int z = rem / gy;

    const int t = threadIdx.x;
    const int lane = t & 63, wid = t >> 6;
    const int wr = wid >> 2, wc = wid & 3;           // 2 x 4 wave grid
    const int tileM = by * 256, tileN = bx * 256;
    A += (size_t)z * aZ;
    B += (size_t)z * bZ;

    f32x4 acc[8][4] = {};

    // ---- read geometry: frag element k = kk*32 + qw*8 (qw = lane>>4);
    // granule g = kk*4+qw; physical g^(row&7), row&7 == lane&7.
    const int l4 = lane & 15, qw = lane >> 4, sw = lane & 7;
    const int aoff0 = l4 * 64 + ((qw ^ sw) << 3);
    const int aoff1 = l4 * 64 + (((4 | qw) ^ sw) << 3);

    // per-wave LDS read bases (compile-time buffer indices)
    const unsigned short* aB0 = &lds[0][wr][0];
    const unsigned short* aB1 = &lds[1][wr][0];
    const unsigned short* bB0 = &lds[0][2 + (wc >> 1)][0] + (wc & 1) * 4096;
    const unsigned short* bB1 = &lds[1][2 + (wc >> 1)][0] + (wc & 1) * 4096;

    // staging dest bases
    char* const ldsA[2] = {(char*)&lds[0][0][0], (char*)&lds[1][0][0]};
    char* const ldsB[2] = {(char*)&lds[0][2][0], (char*)&lds[1][2][0]};

    // ---- staging geometry: half-tile = 128 rows x 64 K, 2 gload16/thread.
    // row = t>>3 (+64), phys granule = t&7, src granule = (t ^ (t>>3)) & 7.
    const int srow = t >> 3;
    const int sg = ((t ^ (t >> 3)) & 7) << 3;
    const unsigned short* Asrc0 = A + (size_t)(tileM + srow) * lda + sg;
    const unsigned short* Asrc1 = Asrc0 + (size_t)128 * lda;
    const unsigned short* Bsrc0 = B + (size_t)(tileN + srow) * ldb + sg;
    const unsigned short* Bsrc1 = Bsrc0 + (size_t)128 * ldb;

    auto stageA = [&](char* Lb, int koff, int h) {
        char* dst = Lb + h * 16384 + wid * 1024;
        const unsigned short* s = (h ? Asrc1 : Asrc0) + koff;
        gload16(s, dst);
        gload16(s + (size_t)64 * lda, dst + 8192);
    };
    auto stageB = [&](char* Lb, int koff, int h) {
        char* dst = Lb + h * 16384 + wid * 1024;
        const unsigned short* s = (h ? Bsrc1 : Bsrc0) + koff;
        gload16(s, dst);
        gload16(s + (size_t)64 * ldb, dst + 8192);
    };

    const int NT = K >> 6;            // BK=64; K % 128 == 0 here -> NT even
    const int NI = NT >> 1;

    // prologue: tile0 fully + B halves of tile1; seal tile0 (B(1) flies).
    stageA(ldsA[0], 0, 0); stageA(ldsA[0], 0, 1);
    stageB(ldsB[0], 0, 0); stageB(ldsB[0], 0, 1);
    stageB(ldsB[1], 64, 0); stageB(ldsB[1], 64, 1);
    VMC(4);
    BAR;

    bf16x8 af[2][2], bfr[4][2];

#pragma unroll 1
    for (int i = 0; i < NI - 1; ++i) {
        const int kb = i * 128;
        const int ko = kb + 64, ke2 = kb + 128, ko2 = kb + 192;

        // p0
        RD_B(bB0); RD_A(aB0, 0);
        BAR; stageA(ldsA[1], ko, 0);
        MFMA_Q(0)
        // p1
        RD_A(aB0, 2);
        BAR; stageA(ldsA[1], ko, 1);
        MFMA_Q(2)
        // p2
        RD_A(aB0, 4);
        BAR; stageB(ldsB[0], ke2, 0);
        MFMA_Q(4)
        // p3: seal tile o (newest half B0(e+2) may fly)
        RD_A(aB0, 6);
        VMC(2);
        BAR; stageB(ldsB[0], ke2, 1);
        MFMA_Q(6)
        // p4
        RD_B(bB1); RD_A(aB1, 0);
        BAR; stageA(ldsA[0], ke2, 0);
        MFMA_Q(0)
        // p5
        RD_A(aB1, 2);
        BAR; stageA(ldsA[0], ke2, 1);
        MFMA_Q(2)
        // p6
        RD_A(aB1, 4);
        BAR; stageB(ldsB[1], ko2, 0);
        MFMA_Q(4)
        // p7: seal tile e+2 (newest half B0(o+2) may fly)
        RD_A(aB1, 6);
        VMC(2);
        BAR; stageB(ldsB[1], ko2, 1);
        MFMA_Q(6)
    }

    {   // ---- peeled final iteration (no future stages)
        const int ko = (NI - 1) * 128 + 64;
        RD_B(bB0); RD_A(aB0, 0);
        BAR; stageA(ldsA[1], ko, 0);
        MFMA_Q(0)
        RD_A(aB0, 2);
        BAR; stageA(ldsA[1], ko, 1);
        MFMA_Q(2)
        RD_A(aB0, 4);
        BAR;
        MFMA_Q(4)
        RD_A(aB0, 6);
        VMC(0);
        BAR;
        MFMA_Q(6)
        RD_B(bB1); RD_A(aB1, 0);
        BAR;
        MFMA_Q(0)
        RD_A(aB1, 2);
        BAR;
        MFMA_Q(2)
        RD_A(aB1, 4);
        BAR;
        MFMA_Q(4)
        RD_A(aB1, 6);
        BAR;
        MFMA_Q(6)
    }

    // epilogue: C/D layout col = lane&15, row = (lane>>4)*4 + j  [m89-verified]
    const int lr = lane >> 4, lc = lane & 15;
#pragma unroll
    for (int m = 0; m < 8; ++m) {
#pragma unroll
        for (int n = 0; n < 4; ++n) {
            f32x4 v = acc[m][n];
            const int col = tileN + wc * 64 + n * 16 + lc;
            const int row0 = tileM + wr * 128 + m * 16 + lr * 4;
            if (EPI == 0) {
                const float bv = bias[col];
                if (col < 2048) {
                    unsigned short* dst = (col < 1024) ? (unsigned short*)C0
                                                       : (unsigned short*)C1;
                    const int cc = col & 1023;
#pragma unroll
                    for (int j = 0; j < 4; ++j)
                        dst[(size_t)(row0 + j) * 1024 + cc] = f2b(v[j] + bv);
                } else {
                    // vT[b][col-2048][s], rows row0..row0+3 are consecutive s
                    const int b = row0 >> 12, s = row0 & 4095;
                    ushort4 h4;
                    h4.x = f2b(v[0] + bv); h4.y = f2b(v[1] + bv);
                    h4.z = f2b(v[2] + bv); h4.w = f2b(v[3] + bv);
                    *(ushort4*)((unsigned short*)C2 +
                                ((size_t)b * 1024 + (col - 2048)) * 4096 + s) = h4;
                }
            } else if (EPI == 1) {
#pragma unroll
                for (int j = 0; j < 4; ++j)
                    ((_Float16*)C0)[(size_t)z * cZ + (size_t)(row0 + j) * ldc + col] =
                        (_Float16)(v[j] * scale);
            } else if (EPI == 2) {
#pragma unroll
                for (int j = 0; j < 4; ++j)
                    ((unsigned short*)C0)[(size_t)z * cZ + (size_t)(row0 + j) * ldc + col] =
                        f2b(v[j]);
            } else {
#pragma unroll
                for (int j = 0; j < 4; ++j)
                    ((float*)C0)[(size_t)(row0 + j) * ldc + col] = v[j] + bias[col];
            }
        }
    }
}

// ---------------------------------------------------------------------------
// Row softmax in-place: reads 4096 f16, writes 4096 bf16 over the same bytes.
// BW-bound (~41us at 6.3 TB/s floor; __expf measured null in r10).
// ---------------------------------------------------------------------------
__global__ __launch_bounds__(256) void softmax_rows(unsigned short* __restrict__ sc)
{
    const size_t rowoff = (size_t)blockIdx.x * 4096;
    const int t = threadIdx.x;

    h8 a = *(const h8*)(sc + rowoff + t * 8);
    h8 b = *(const h8*)(sc + rowoff + 2048 + t * 8);
    float v[16];
#pragma unroll
    for (int i = 0; i < 8; ++i) { v[i] = (float)a[i]; v[8 + i] = (float)b[i]; }

    float mx = -1e30f;
#pragma unroll
    for (int i = 0; i < 16; ++i) mx = fmaxf(mx, v[i]);
#pragma unroll
    for (int o = 32; o > 0; o >>= 1) mx = fmaxf(mx, __shfl_xor(mx, o));
    __shared__ float redm[4];
    if ((t & 63) == 0) redm[t >> 6] = mx;
    __syncthreads();
    mx = fmaxf(fmaxf(redm[0], redm[1]), fmaxf(redm[2], redm[3]));

    float sum = 0.f;
#pragma unroll
    for (int i = 0; i < 16; ++i) { v[i] = expf(v[i] - mx); sum += v[i]; }
#pragma unroll
    for (int o = 32; o > 0; o >>= 1) sum += __shfl_xor(sum, o);
    __shared__ float reds[4];
    if ((t & 63) == 0) reds[t >> 6] = sum;
    __syncthreads();
    sum = reds[0] + reds[1] + reds[2] + reds[3];
    const float rs = 1.f / sum;

    u16x8 w0, w1;
#pragma unroll
    for (int i = 0; i < 8; ++i) {
        w0[i] = f2b(v[i] * rs);
        w1[i] = f2b(v[8 + i] * rs);
    }
    *(u16x8*)(sc + rowoff + t * 8) = w0;
    *(u16x8*)(sc + rowoff + 2048 + t * 8) = w1;
}

__global__ __launch_bounds__(256) void cast_bf16(
    const float* __restrict__ in, unsigned short* __restrict__ out, int n4)
{
    const int i = blockIdx.x * 256 + threadIdx.x;
    if (i < n4) {
        float4 f = ((const float4*)in)[i];
        ushort4 o;
        o.x = f2b(f.x); o.y = f2b(f.y); o.z = f2b(f.z); o.w = f2b(f.w);
        ((ushort4*)out)[i] = o;
    }
}

// ---------------------------------------------------------------------------
extern "C" void kernel_launch(void* const* d_in, const int* in_sizes, int n_in,
                              void* d_out, int out_size, void* d_ws, size_t ws_size,
                              hipStream_t stream)
{
    const float* x      = (const float*)d_in[0];   // [4,4096,1024]
    const float* qkv_w  = (const float*)d_in[1];   // [3072,1024]
    const float* qkv_b  = (const float*)d_in[2];   // [3072]
    const float* out_w  = (const float*)d_in[3];   // [1024,1024]
    const float* out_b  = (const float*)d_in[4];   // [1024]
    float* out = (float*)d_out;                    // [4,4096,1024] fp32

    unsigned short* W = (unsigned short*)d_ws;
    const size_t M16 = 16777216;   // one [4,4096,1024] bf16 tensor (ushorts)

    if (ws_size >= 236978176ull) {
        // ---- big mode: 226 MiB peak ----
        unsigned short* sc   = W;
        unsigned short* q    = sc + 67108864;
        unsigned short* kk   = q + M16;
        unsigned short* vT   = kk + M16;
        unsigned short* wo   = vT + M16;
        unsigned short* xb   = sc;            // transient, dead before sc write
        unsigned short* wqkv = sc + M16;      // transient
        unsigned short* ao   = q;             // q dead after scores GEMM

        cast_bf16<<<16384, 256, 0, stream>>>(x, xb, 4194304);
        cast_bf16<<<3072, 256, 0, stream>>>(qkv_w, wqkv, 786432);
        cast_bf16<<<1024, 256, 0, stream>>>(out_w, wo, 262144);

        gemm_nt<0, 0><<<12 * 64, 512, 0, stream>>>(
            xb, wqkv, 0, 0, 1024, 1024, 1024, qkv_b, q, kk, vT, 0, 0, 0.f, 12, 64);

        gemm_nt<1, 0><<<16 * 16 * 4, 512, 0, stream>>>(
            q, kk, 4194304, 4194304, 1024, 1024, 1024, nullptr,
            sc, nullptr, nullptr, 16777216, 4096, 0.03125f, 16, 16);

        softmax_rows<<<16384, 256, 0, stream>>>(sc);

        gemm_nt<2, 1><<<4 * 16 * 4, 512, 0, stream>>>(
            sc, vT, 16777216, 4194304, 4096, 4096, 4096, nullptr,
            ao, nullptr, nullptr, 4194304, 1024, 0.f, 4, 16);

        gemm_nt<3, 0><<<4 * 64, 512, 0, stream>>>(
            ao, wo, 0, 0, 1024, 1024, 1024, out_b,
            out, nullptr, nullptr, 0, 1024, 0.f, 4, 64);
    } else {
        // ---- small mode: 168 MiB peak, per-batch scores buffer ----
        unsigned short* sc   = W;
        unsigned short* q    = sc + M16;
        unsigned short* kk   = q + M16;
        unsigned short* vT   = kk + M16;
        unsigned short* ao   = vT + M16;
        unsigned short* wo   = ao + M16;
        unsigned short* wqkv = wo + 1048576;
        unsigned short* xb   = sc;

        cast_bf16<<<16384, 256, 0, stream>>>(x, xb, 4194304);
        cast_bf16<<<3072, 256, 0, stream>>>(qkv_w, wqkv, 786432);
        cast_bf16<<<1024, 256, 0, stream>>>(out_w, wo, 262144);

        gemm_nt<0, 0><<<12 * 64, 512, 0, stream>>>(
            xb, wqkv, 0, 0, 1024, 1024, 1024, qkv_b, q, kk, vT, 0, 0, 0.f, 12, 64);

        for (int z = 0; z < 4; ++z) {
            const size_t zo = (size_t)z * 4194304;
            gemm_nt<1, 0><<<16 * 16, 512, 0, stream>>>(
                q + zo, kk + zo, 0, 0, 1024, 1024, 1024, nullptr,
                sc, nullptr, nullptr, 0, 4096, 0.03125f, 16, 16);
            softmax_rows<<<4096, 256, 0, stream>>>(sc);
            gemm_nt<2, 1><<<4 * 16, 512, 0, stream>>>(
                sc, vT + zo, 0, 0, 4096, 4096, 4096, nullptr,
                ao + zo, nullptr, nullptr, 0, 1024, 0.f, 4, 16);
        }

        gemm_nt<3, 0><<<4 * 64, 512, 0, stream>>>(
            ao, wo, 0, 0, 1024, 1024, 1024, out_b,
            out, nullptr, nullptr, 0, 1024, 0.f, 4, 64);
    }
}